// Round 8
// baseline (124.396 us; speedup 1.0000x reference)
//
#include <hip/hip_runtime.h>
#include <hip/hip_bf16.h>
#include <math.h>

// FlexMaxPool: segment_max(features[in_idx], out_idx, num_segments=N_POINTS)
// R24 = R21 binsort (verbatim) + channel-split XCD-pinned pool.
//  - Arithmetic: pool gather = 1.6M x 128B = 205MB; ~1900 distinct rows/bin,
//    ~4% inter-bin overlap -> no L2 reuse -> 205MB streams from L3 at ~6TB/s
//    (random 128B) ~= 33us ~= measured pool time. Pool is L3-BW-bound.
//  - R19 (temporal phasing) failed for lack of cross-block alignment; R24 does
//    it SPATIALLY: 2 blocks per bin, one per channel half (64B of each row).
//    bid%8 XCD round-robin (T1-measured) pins half 0 -> XCDs 0-3, half 1 ->
//    XCDs 4-7: per-XCD gather set = 3.2MB -> RESIDENT in 4MB L2. 205MB then
//    runs at L2 BW (~6us) + ~26MB cold fill.
//  - Gather: uint2/lane (4 ch), same instr count & iterations as R21; pk_max
//    halves. Cost: list copy+sort duplicated per half (~+5us). Perm dropped
//    (R23 neutral).
//  - If bid%8 mapping is false: expect +3-5us (duplication only) -> falsifies.
//  - dur_us carries ~48us fixed harness fills (ws 256MiB + out 12.8MB).
//
// ws: feat16 6.4MB | chunkdata 256x6256 u32 (6.4MB) | pfxg 256x1024 u32 (1MB)

#define N_POINTS 50000
#define N_EDGES  1600000
#define CHANNELS 64
#define BIN_SHIFT 6
#define BIN_PTS   64
#define NBINS     782              // ceil(50000/64)
#define NBINS_PAD 1024
#define CAPL      2560             // per-bin list capacity (mean 2046, +11 sigma)
#define QCAP      2560
#define P1_GRID   256
#define P1_BLK    1024
#define ECHUNK    (N_EDGES / P1_GRID)               // 6250, exact
#define ECHUNK_PAD 6256                             // next multiple of 4
#define CVT_TOTAL (N_POINTS * CHANNELS / 4)         // 800000 float4
#define CVT_PER   ((CVT_TOTAL + P1_GRID - 1) / P1_GRID)   // 3125
#define P2_GRID   1568                              // 8 * 196 >= 2*NBINS

__device__ __forceinline__ unsigned int encode_bf16(float x) {
    unsigned int u = __float_as_uint(x);
    unsigned int r = ((u >> 16) & 1u) + 0x7FFFu;
    unsigned int h = (u + r) >> 16;
    return (h & 0x8000u) ? (h ^ 0xFFFFu) : (h | 0x8000u);
}

__device__ __forceinline__ float decode_u16(unsigned int v) {
    if (v == 0u) return -INFINITY;
    unsigned int h = (v & 0x8000u) ? (v ^ 0x8000u) : (v ^ 0xFFFFu);
    return __uint_as_float(h << 16);
}

__device__ __forceinline__ unsigned int pk_max_u16(unsigned int a, unsigned int b) {
    unsigned int d;
    asm("v_pk_max_u16 %0, %1, %2" : "=v"(d) : "v"(a), "v"(b));
    return d;
}

// Counting sort of a 6250-edge chunk by 64-pt bin (dst>>6) into LDS, then a
// fully-coalesced contiguous dump (uint4) + per-chunk prefix table. Also this
// block's slice of the feature conversion.
// Entry: (bin:10 | dst_local:6 | src:16).   [R21 verbatim]
__global__ __launch_bounds__(P1_BLK) void binsort_cvt_kernel(
    const int2*   __restrict__ idx,
    const float4* __restrict__ feat4,
    uint2*        __restrict__ f16o,
    unsigned int* __restrict__ chunkd,
    unsigned int* __restrict__ pfxg)
{
    __shared__ unsigned int hist[NBINS_PAD];
    __shared__ unsigned int pfx[NBINS_PAD];
    __shared__ __align__(16) unsigned int staging[ECHUNK_PAD];   // 25 KB
    __shared__ unsigned int wsum[16];

    int tid  = threadIdx.x;
    int lane = tid & 63, w = tid >> 6;

    // ---- feature-convert slice (independent; overlaps the sort's LDS phases) ----
    {
        int cb = blockIdx.x * CVT_PER;
        #pragma unroll
        for (int k = 0; k < 4; ++k) {
            int i = cb + k * P1_BLK + tid;
            if (i < cb + CVT_PER && i < CVT_TOTAL) {
                float4 v = feat4[i];
                uint2 r;
                r.x = encode_bf16(v.x) | (encode_bf16(v.y) << 16);
                r.y = encode_bf16(v.z) | (encode_bf16(v.w) << 16);
                f16o[i] = r;
            }
        }
    }

    // ---- counting sort ----
    int base = blockIdx.x * ECHUNK;

    hist[tid] = 0u;
    __syncthreads();

    int2 e[7]; unsigned int slot[7];
    #pragma unroll
    for (int j = 0; j < 7; ++j) {
        int i = j * P1_BLK + tid;
        if (i < ECHUNK) {
            e[j] = idx[base + i];
            slot[j] = atomicAdd(&hist[(unsigned)e[j].x >> BIN_SHIFT], 1u);
        }
    }
    __syncthreads();

    // Exclusive prefix over 1024 bins, all 16 waves participating.
    {
        unsigned int a = hist[tid];
        unsigned int inc = a;
        #pragma unroll
        for (int d = 1; d < 64; d <<= 1) {
            unsigned int v = __shfl_up(inc, d, 64);
            if (lane >= d) inc += v;
        }
        if (lane == 63) wsum[w] = inc;
        __syncthreads();
        unsigned int woff = 0;
        #pragma unroll
        for (int k = 0; k < 16; ++k) if (k < w) woff += wsum[k];
        pfx[tid] = woff + inc - a;
    }
    __syncthreads();

    #pragma unroll
    for (int j = 0; j < 7; ++j) {
        int i = j * P1_BLK + tid;
        if (i < ECHUNK) {
            unsigned int dst = (unsigned)e[j].x, src = (unsigned)e[j].y;
            unsigned int bin = dst >> BIN_SHIFT;
            staging[pfx[bin] + slot[j]] =
                (bin << 22) | ((dst & (BIN_PTS - 1)) << 16) | src;
        }
    }
    if (tid < ECHUNK_PAD - ECHUNK) staging[ECHUNK + tid] = 0u;   // dump pad
    __syncthreads();

    // Fully-coalesced dump: 1564 uint4 + 1024-entry prefix table.
    {
        const uint4* st4 = (const uint4*)staging;
        uint4* cd4 = (uint4*)(chunkd + (size_t)blockIdx.x * ECHUNK_PAD);
        #pragma unroll
        for (int k = 0; k < 2; ++k) {
            int i = k * P1_BLK + tid;
            if (i < ECHUNK_PAD / 4) cd4[i] = st4[i];
        }
        pfxg[blockIdx.x * NBINS_PAD + tid] = pfx[tid];
    }
}

// Two blocks per 64-pt bin (one per channel half); 512 threads. bid%8 pins
// half 0 to XCDs 0-3, half 1 to XCDs 4-7 -> per-XCD gather set = 3.2MB,
// L2-resident. Prologue (per half-block): concat the bin's 256 chunk-segments
// into LDS, LDS sort by point. Gather: 8-lane group per point, uint2/lane
// (4 channels), 8 pk_max chains (4-deep unroll).
__global__ __launch_bounds__(512) void pool_kernel(
    const unsigned int* __restrict__ feat16,   // (N_POINTS, 32) u32: 2 encoded u16
    const unsigned int* __restrict__ chunkd,
    const unsigned int* __restrict__ pfxg,
    float4* __restrict__ out4)
{
    __shared__ unsigned int list[CAPL];        // 10 KB
    __shared__ unsigned int sorted[QCAP];      // 10 KB
    __shared__ unsigned int choff[P1_GRID];
    __shared__ unsigned int hist[64];
    __shared__ unsigned int start[65];
    __shared__ unsigned int cur[64];
    __shared__ unsigned int wsum4[4];
    __shared__ unsigned int Tsh;

    int tid = threadIdx.x;
    int bid = blockIdx.x;
    // bid%8 -> XCD (measured round-robin). bid&7 in 0..3 -> half 0, 4..7 -> half 1.
    int half = (bid >> 2) & 1;
    int bin  = (bid >> 3) * 4 + (bid & 3);
    if (bin >= NBINS) return;

    int lane = tid & 63, w = tid >> 6;

    if (tid < 64) hist[tid] = 0u;

    // Per-chunk segment bounds + exclusive scan of counts (4 waves).
    unsigned int cntc = 0, inc = 0;
    if (tid < P1_GRID) {
        unsigned int s = pfxg[tid * NBINS_PAD + bin];
        unsigned int e = pfxg[tid * NBINS_PAD + bin + 1];
        cntc = e - s;
        inc = cntc;
        #pragma unroll
        for (int d = 1; d < 64; d <<= 1) {
            unsigned int v = __shfl_up(inc, d, 64);
            if (lane >= d) inc += v;
        }
        if (lane == 63) wsum4[w] = inc;
    }
    __syncthreads();
    if (tid < P1_GRID) {
        unsigned int woff = 0;
        #pragma unroll
        for (int k = 0; k < 4; ++k) if (k < w) woff += wsum4[k];
        unsigned int off = woff + inc - cntc;
        choff[tid] = off;
        if (tid == P1_GRID - 1) Tsh = off + cntc;
    }
    __syncthreads();

    unsigned int T = Tsh; if (T > CAPL) T = CAPL;

    // Copy segments: 2 threads per chunk (interleaved halves).
    {
        int c = tid >> 1, h = tid & 1;
        unsigned int s = pfxg[c * NBINS_PAD + bin];
        unsigned int e = pfxg[c * NBINS_PAD + bin + 1];
        unsigned int n = e - s;
        unsigned int off = choff[c];
        unsigned int g0 = (unsigned)c * ECHUNK_PAD + s;
        for (unsigned int j = h; j < n; j += 2) {
            unsigned int v = chunkd[g0 + j];
            if (off + j < CAPL) list[off + j] = v;
        }
    }
    __syncthreads();

    // Histogram the bin's entries over 64 points.
    for (unsigned int t = tid; t < T; t += 512)
        atomicAdd(&hist[(list[t] >> 16) & 63], 1u);
    __syncthreads();

    // Scan 64 sub-bins with wave 0.
    if (tid < 64) {
        unsigned int h = hist[tid], inc2 = h;
        #pragma unroll
        for (int d = 1; d < 64; d <<= 1) {
            unsigned int v = __shfl_up(inc2, d, 64);
            if (tid >= d) inc2 += v;
        }
        start[tid] = inc2 - h; cur[tid] = inc2 - h;
        if (tid == 63) start[64] = inc2;
    }
    __syncthreads();

    for (unsigned int t = tid; t < T; t += 512) {
        unsigned int v = list[t];
        unsigned int slot = atomicAdd(&cur[(v >> 16) & 63], 1u);
        if (slot < QCAP) sorted[slot] = (v & 0xFFFFu) << 4;   // src * 16 uint2-rows
    }
    __syncthreads();

    // 8-lane group per point: lane ln holds channels half*32 + ln*4 .. +3
    // (one uint2 of the feature row).
    const uint2* frow2 = (const uint2*)feat16;
    int g = tid >> 3, ln = tid & 7;
    unsigned int hoff = (unsigned)half * 8 + (unsigned)ln;   // uint2 offset in row
    unsigned int s0 = start[g], s1 = start[g + 1];
    if (s1 > QCAP) s1 = QCAP;

    unsigned int A0=0,A1=0, B0=0,B1=0, C0=0,C1=0, D0=0,D1=0;
    unsigned int i = s0;
    for (; i + 4 <= s1; i += 4) {
        unsigned int r0 = sorted[i+0], r1 = sorted[i+1];
        unsigned int r2 = sorted[i+2], r3 = sorted[i+3];
        uint2 u0 = frow2[r0 + hoff];
        uint2 u1 = frow2[r1 + hoff];
        uint2 u2 = frow2[r2 + hoff];
        uint2 u3 = frow2[r3 + hoff];
        A0 = pk_max_u16(A0, u0.x); A1 = pk_max_u16(A1, u0.y);
        B0 = pk_max_u16(B0, u1.x); B1 = pk_max_u16(B1, u1.y);
        C0 = pk_max_u16(C0, u2.x); C1 = pk_max_u16(C1, u2.y);
        D0 = pk_max_u16(D0, u3.x); D1 = pk_max_u16(D1, u3.y);
    }
    for (; i < s1; ++i) {
        uint2 u = frow2[sorted[i] + hoff];
        A0 = pk_max_u16(A0, u.x); A1 = pk_max_u16(A1, u.y);
    }
    A0 = pk_max_u16(pk_max_u16(A0, B0), pk_max_u16(C0, D0));
    A1 = pk_max_u16(pk_max_u16(A1, B1), pk_max_u16(C1, D1));

    int gp = bin * BIN_PTS + g;
    if (gp < N_POINTS) {
        float4 o;
        o.x = decode_u16(A0 & 0xFFFFu); o.y = decode_u16(A0 >> 16);
        o.z = decode_u16(A1 & 0xFFFFu); o.w = decode_u16(A1 >> 16);
        out4[(size_t)gp * 16 + hoff] = o;
    }
}

extern "C" void kernel_launch(void* const* d_in, const int* in_sizes, int n_in,
                              void* d_out, int out_size, void* d_ws, size_t ws_size,
                              hipStream_t stream) {
    const float4* feat4 = (const float4*)d_in[0];
    const int2*   idx   = (const int2*)d_in[1];

    size_t off_feat16 = 0;
    size_t off_chunk  = (size_t)N_POINTS * CHANNELS * 2;                 // 6.4 MB
    size_t off_pfxg   = off_chunk + (size_t)P1_GRID * ECHUNK_PAD * 4;    // +6.4 MB
    uint2*        f16o   = (uint2*)((char*)d_ws + off_feat16);
    unsigned int* feat16 = (unsigned int*)((char*)d_ws + off_feat16);
    unsigned int* chunkd = (unsigned int*)((char*)d_ws + off_chunk);
    unsigned int* pfxg   = (unsigned int*)((char*)d_ws + off_pfxg);

    binsort_cvt_kernel<<<P1_GRID, P1_BLK, 0, stream>>>(idx, feat4, f16o, chunkd, pfxg);
    pool_kernel<<<P2_GRID, 512, 0, stream>>>(feat16, chunkd, pfxg, (float4*)d_out);
}

// Round 9
// 105.078 us; speedup vs baseline: 1.1838x; 1.1838x over previous
//
#include <hip/hip_runtime.h>
#include <hip/hip_bf16.h>
#include <math.h>

// FlexMaxPool: segment_max(features[in_idx], out_idx, num_segments=N_POINTS)
// R25 = R21 (best, 104.6us) + 6-deep MLP gather.
//  - R24 post-mortem: channel-split REGRESSED (+20us) but exposed pool PMC:
//    50.7us, FETCH 117MB, 2.6TB/s (33% peak), VALU 17%, occ 58%.
//    (a) bid%8 XCD pinning FALSIFIED: FETCH stayed at no-reuse level (~117MB),
//        not the ~26MB cold-fill level L2-residency would give.
//    (b) 33% BW + 17% VALU => gather is LATENCY-bound (too few outstanding
//        loads), not BW-bound. R24 also inverted the R18 width lever.
//  - R25: R21 verbatim, except the gather unrolls 6-deep (6 outstanding uint4
//    per wave vs 4; 16 pk_max chains reused u4->A, u5->B). VGPR ~55 stays
//    under the 64-reg / 8-waves-per-SIMD cliff (why not 8-deep).
//  - dur_us carries ~48us fixed harness fills (ws 256MiB + out 12.8MB).
//
// ws: feat16 6.4MB | chunkdata 256x6256 u32 (6.4MB) | pfxg 256x1024 u32 (1MB)

#define N_POINTS 50000
#define N_EDGES  1600000
#define CHANNELS 64
#define BIN_SHIFT 6
#define BIN_PTS   64
#define NBINS     782              // ceil(50000/64)
#define NBINS_PAD 1024
#define CAPL      2560             // per-bin list capacity (mean 2046, +11 sigma)
#define QCAP      2560
#define P1_GRID   256
#define P1_BLK    1024
#define ECHUNK    (N_EDGES / P1_GRID)               // 6250, exact
#define ECHUNK_PAD 6256                             // next multiple of 4
#define CVT_TOTAL (N_POINTS * CHANNELS / 4)         // 800000 float4
#define CVT_PER   ((CVT_TOTAL + P1_GRID - 1) / P1_GRID)   // 3125

__device__ __forceinline__ unsigned int encode_bf16(float x) {
    unsigned int u = __float_as_uint(x);
    unsigned int r = ((u >> 16) & 1u) + 0x7FFFu;
    unsigned int h = (u + r) >> 16;
    return (h & 0x8000u) ? (h ^ 0xFFFFu) : (h | 0x8000u);
}

__device__ __forceinline__ float decode_u16(unsigned int v) {
    if (v == 0u) return -INFINITY;
    unsigned int h = (v & 0x8000u) ? (v ^ 0x8000u) : (v ^ 0xFFFFu);
    return __uint_as_float(h << 16);
}

__device__ __forceinline__ unsigned int pk_max_u16(unsigned int a, unsigned int b) {
    unsigned int d;
    asm("v_pk_max_u16 %0, %1, %2" : "=v"(d) : "v"(a), "v"(b));
    return d;
}

// Counting sort of a 6250-edge chunk by 64-pt bin (dst>>6) into LDS, then a
// fully-coalesced contiguous dump (uint4) + per-chunk prefix table. Also this
// block's slice of the feature conversion.
// Entry: (bin:10 | dst_local:6 | src:16).   [R21 verbatim]
__global__ __launch_bounds__(P1_BLK) void binsort_cvt_kernel(
    const int2*   __restrict__ idx,
    const float4* __restrict__ feat4,
    uint2*        __restrict__ f16o,
    unsigned int* __restrict__ chunkd,
    unsigned int* __restrict__ pfxg)
{
    __shared__ unsigned int hist[NBINS_PAD];
    __shared__ unsigned int pfx[NBINS_PAD];
    __shared__ __align__(16) unsigned int staging[ECHUNK_PAD];   // 25 KB
    __shared__ unsigned int wsum[16];

    int tid  = threadIdx.x;
    int lane = tid & 63, w = tid >> 6;

    // ---- feature-convert slice (independent; overlaps the sort's LDS phases) ----
    {
        int cb = blockIdx.x * CVT_PER;
        #pragma unroll
        for (int k = 0; k < 4; ++k) {
            int i = cb + k * P1_BLK + tid;
            if (i < cb + CVT_PER && i < CVT_TOTAL) {
                float4 v = feat4[i];
                uint2 r;
                r.x = encode_bf16(v.x) | (encode_bf16(v.y) << 16);
                r.y = encode_bf16(v.z) | (encode_bf16(v.w) << 16);
                f16o[i] = r;
            }
        }
    }

    // ---- counting sort ----
    int base = blockIdx.x * ECHUNK;

    hist[tid] = 0u;
    __syncthreads();

    int2 e[7]; unsigned int slot[7];
    #pragma unroll
    for (int j = 0; j < 7; ++j) {
        int i = j * P1_BLK + tid;
        if (i < ECHUNK) {
            e[j] = idx[base + i];
            slot[j] = atomicAdd(&hist[(unsigned)e[j].x >> BIN_SHIFT], 1u);
        }
    }
    __syncthreads();

    // Exclusive prefix over 1024 bins, all 16 waves participating.
    {
        unsigned int a = hist[tid];
        unsigned int inc = a;
        #pragma unroll
        for (int d = 1; d < 64; d <<= 1) {
            unsigned int v = __shfl_up(inc, d, 64);
            if (lane >= d) inc += v;
        }
        if (lane == 63) wsum[w] = inc;
        __syncthreads();
        unsigned int woff = 0;
        #pragma unroll
        for (int k = 0; k < 16; ++k) if (k < w) woff += wsum[k];
        pfx[tid] = woff + inc - a;
    }
    __syncthreads();

    #pragma unroll
    for (int j = 0; j < 7; ++j) {
        int i = j * P1_BLK + tid;
        if (i < ECHUNK) {
            unsigned int dst = (unsigned)e[j].x, src = (unsigned)e[j].y;
            unsigned int bin = dst >> BIN_SHIFT;
            staging[pfx[bin] + slot[j]] =
                (bin << 22) | ((dst & (BIN_PTS - 1)) << 16) | src;
        }
    }
    if (tid < ECHUNK_PAD - ECHUNK) staging[ECHUNK + tid] = 0u;   // dump pad
    __syncthreads();

    // Fully-coalesced dump: 1564 uint4 + 1024-entry prefix table.
    {
        const uint4* st4 = (const uint4*)staging;
        uint4* cd4 = (uint4*)(chunkd + (size_t)blockIdx.x * ECHUNK_PAD);
        #pragma unroll
        for (int k = 0; k < 2; ++k) {
            int i = k * P1_BLK + tid;
            if (i < ECHUNK_PAD / 4) cd4[i] = st4[i];
        }
        pfxg[blockIdx.x * NBINS_PAD + tid] = pfx[tid];
    }
}

// One block per 64-pt bin; 512 threads. Prologue: concatenate the bin's 256
// chunk-segments (via pfxg) into LDS list[]. LDS sort by point, then 8-lane
// group per point, uint4 gather (8 ch/lane), 16 pk_max chains, 6-deep unroll
// (6 outstanding loads/wave).
__global__ __launch_bounds__(512) void pool_kernel(
    const unsigned int* __restrict__ feat16,   // (N_POINTS, 32) u32: 2 encoded u16
    const unsigned int* __restrict__ chunkd,
    const unsigned int* __restrict__ pfxg,
    float4* __restrict__ out4)
{
    __shared__ unsigned int list[CAPL];        // 10 KB
    __shared__ unsigned int sorted[QCAP];      // 10 KB
    __shared__ unsigned int choff[P1_GRID];
    __shared__ unsigned int hist[64];
    __shared__ unsigned int start[65];
    __shared__ unsigned int cur[64];
    __shared__ unsigned int wsum4[4];
    __shared__ unsigned int Tsh;

    int tid = threadIdx.x;
    int bin = blockIdx.x;
    int lane = tid & 63, w = tid >> 6;

    if (tid < 64) hist[tid] = 0u;

    // Per-chunk segment bounds + exclusive scan of counts (4 waves).
    unsigned int cntc = 0, inc = 0;
    if (tid < P1_GRID) {
        unsigned int s = pfxg[tid * NBINS_PAD + bin];
        unsigned int e = pfxg[tid * NBINS_PAD + bin + 1];
        cntc = e - s;
        inc = cntc;
        #pragma unroll
        for (int d = 1; d < 64; d <<= 1) {
            unsigned int v = __shfl_up(inc, d, 64);
            if (lane >= d) inc += v;
        }
        if (lane == 63) wsum4[w] = inc;
    }
    __syncthreads();
    if (tid < P1_GRID) {
        unsigned int woff = 0;
        #pragma unroll
        for (int k = 0; k < 4; ++k) if (k < w) woff += wsum4[k];
        unsigned int off = woff + inc - cntc;
        choff[tid] = off;
        if (tid == P1_GRID - 1) Tsh = off + cntc;
    }
    __syncthreads();

    unsigned int T = Tsh; if (T > CAPL) T = CAPL;

    // Copy segments: 2 threads per chunk (interleaved halves).
    {
        int c = tid >> 1, h = tid & 1;
        unsigned int s = pfxg[c * NBINS_PAD + bin];
        unsigned int e = pfxg[c * NBINS_PAD + bin + 1];
        unsigned int n = e - s;
        unsigned int off = choff[c];
        unsigned int g0 = (unsigned)c * ECHUNK_PAD + s;
        for (unsigned int j = h; j < n; j += 2) {
            unsigned int v = chunkd[g0 + j];
            if (off + j < CAPL) list[off + j] = v;
        }
    }
    __syncthreads();

    // Histogram the bin's entries over 64 points.
    for (unsigned int t = tid; t < T; t += 512)
        atomicAdd(&hist[(list[t] >> 16) & 63], 1u);
    __syncthreads();

    // Scan 64 sub-bins with wave 0.
    if (tid < 64) {
        unsigned int h = hist[tid], inc2 = h;
        #pragma unroll
        for (int d = 1; d < 64; d <<= 1) {
            unsigned int v = __shfl_up(inc2, d, 64);
            if (tid >= d) inc2 += v;
        }
        start[tid] = inc2 - h; cur[tid] = inc2 - h;
        if (tid == 63) start[64] = inc2;
    }
    __syncthreads();

    for (unsigned int t = tid; t < T; t += 512) {
        unsigned int v = list[t];
        unsigned int slot = atomicAdd(&cur[(v >> 16) & 63], 1u);
        if (slot < QCAP) sorted[slot] = (v & 0xFFFFu) << 3;   // src * 8 uint4-rows
    }
    __syncthreads();

    // 8-lane group per point: lane ln holds channels 8*ln..8*ln+7 (one uint4).
    // 6-deep unroll: 6 outstanding uint4 loads per wave (latency hiding).
    const uint4* frow = (const uint4*)feat16;
    int g = tid >> 3, ln = tid & 7;
    unsigned int s0 = start[g], s1 = start[g + 1];
    if (s1 > QCAP) s1 = QCAP;

    unsigned int A0=0,A1=0,A2=0,A3=0, B0=0,B1=0,B2=0,B3=0;
    unsigned int C0=0,C1=0,C2=0,C3=0, D0=0,D1=0,D2=0,D3=0;
    unsigned int i = s0;
    for (; i + 6 <= s1; i += 6) {
        unsigned int r0 = sorted[i+0], r1 = sorted[i+1];
        unsigned int r2 = sorted[i+2], r3 = sorted[i+3];
        unsigned int r4 = sorted[i+4], r5 = sorted[i+5];
        uint4 u0 = frow[r0 + ln];
        uint4 u1 = frow[r1 + ln];
        uint4 u2 = frow[r2 + ln];
        uint4 u3 = frow[r3 + ln];
        uint4 u4 = frow[r4 + ln];
        uint4 u5 = frow[r5 + ln];
        A0 = pk_max_u16(A0, u0.x); A1 = pk_max_u16(A1, u0.y);
        A2 = pk_max_u16(A2, u0.z); A3 = pk_max_u16(A3, u0.w);
        B0 = pk_max_u16(B0, u1.x); B1 = pk_max_u16(B1, u1.y);
        B2 = pk_max_u16(B2, u1.z); B3 = pk_max_u16(B3, u1.w);
        C0 = pk_max_u16(C0, u2.x); C1 = pk_max_u16(C1, u2.y);
        C2 = pk_max_u16(C2, u2.z); C3 = pk_max_u16(C3, u2.w);
        D0 = pk_max_u16(D0, u3.x); D1 = pk_max_u16(D1, u3.y);
        D2 = pk_max_u16(D2, u3.z); D3 = pk_max_u16(D3, u3.w);
        A0 = pk_max_u16(A0, u4.x); A1 = pk_max_u16(A1, u4.y);
        A2 = pk_max_u16(A2, u4.z); A3 = pk_max_u16(A3, u4.w);
        B0 = pk_max_u16(B0, u5.x); B1 = pk_max_u16(B1, u5.y);
        B2 = pk_max_u16(B2, u5.z); B3 = pk_max_u16(B3, u5.w);
    }
    for (; i < s1; ++i) {
        uint4 u = frow[sorted[i] + ln];
        A0 = pk_max_u16(A0, u.x); A1 = pk_max_u16(A1, u.y);
        A2 = pk_max_u16(A2, u.z); A3 = pk_max_u16(A3, u.w);
    }
    A0 = pk_max_u16(pk_max_u16(A0, B0), pk_max_u16(C0, D0));
    A1 = pk_max_u16(pk_max_u16(A1, B1), pk_max_u16(C1, D1));
    A2 = pk_max_u16(pk_max_u16(A2, B2), pk_max_u16(C2, D2));
    A3 = pk_max_u16(pk_max_u16(A3, B3), pk_max_u16(C3, D3));

    int gp = bin * BIN_PTS + g;
    if (gp < N_POINTS) {
        float4 o0, o1;
        o0.x = decode_u16(A0 & 0xFFFFu); o0.y = decode_u16(A0 >> 16);
        o0.z = decode_u16(A1 & 0xFFFFu); o0.w = decode_u16(A1 >> 16);
        o1.x = decode_u16(A2 & 0xFFFFu); o1.y = decode_u16(A2 >> 16);
        o1.z = decode_u16(A3 & 0xFFFFu); o1.w = decode_u16(A3 >> 16);
        out4[(size_t)gp * 16 + ln * 2 + 0] = o0;
        out4[(size_t)gp * 16 + ln * 2 + 1] = o1;
    }
}

extern "C" void kernel_launch(void* const* d_in, const int* in_sizes, int n_in,
                              void* d_out, int out_size, void* d_ws, size_t ws_size,
                              hipStream_t stream) {
    const float4* feat4 = (const float4*)d_in[0];
    const int2*   idx   = (const int2*)d_in[1];

    size_t off_feat16 = 0;
    size_t off_chunk  = (size_t)N_POINTS * CHANNELS * 2;                 // 6.4 MB
    size_t off_pfxg   = off_chunk + (size_t)P1_GRID * ECHUNK_PAD * 4;    // +6.4 MB
    uint2*        f16o   = (uint2*)((char*)d_ws + off_feat16);
    unsigned int* feat16 = (unsigned int*)((char*)d_ws + off_feat16);
    unsigned int* chunkd = (unsigned int*)((char*)d_ws + off_chunk);
    unsigned int* pfxg   = (unsigned int*)((char*)d_ws + off_pfxg);

    binsort_cvt_kernel<<<P1_GRID, P1_BLK, 0, stream>>>(idx, feat4, f16o, chunkd, pfxg);
    pool_kernel<<<NBINS, 512, 0, stream>>>(feat16, chunkd, pfxg, (float4*)d_out);
}